// Round 21
// baseline (4653.719 us; speedup 1.0000x reference)
//
#include <hip/hip_runtime.h>
#include <hip/hip_bf16.h>

// LSTM: T=8192, IN=3000, H=100 (4H=400), torch gate order i,f,g,o.
// Phase 1: xg[T][400] = input @ w_ih^T + (b_ih+b_hh), PERMUTED cols (4u+g).
// Phase 2: single-workgroup scan, 256 threads / 4 waves, VALU dot2 engine,
//          weights pinned in PHYSICAL VGPRs (R16/R20-proven mechanism).
// ROUND-21 (K-SPLIT PAIR): R20's step is partially LDS-pipe-bound: 4 waves x
// 13 broadcast ds_read_b128 = 52 shared-pipe slots/step + 8 ds_swizzle slots
// + ~120cyc exchange latency. New split: thread ph=tid&1 owns ALL 4 gate
// rows of unit u=tid>>1 over K-half [50ph,50ph+50): 4x25=100 weight dwords
// in v152..v251; h-half = 25 dwords -> 7 reads/thread (26 slots/step).
// Pair partial sums combined by 4 in-asm DPP quad_perm [1,0,3,2] adds
// (VALU pipe, s_nop-guarded INSIDE the volatile block -- not R17's
// compiler-placed builtin) -> ds_swizzle exchange fully eliminated; both
// lanes compute the identical cell update, even lane writes h.
// h LDS layout: two 16B-aligned 112-byte K-half slices, double-buffered.
// Waits = R16-proven 4-read granularity (lgkmcnt(3) -> lgkmcnt(0)).

#define GBM 128
#define GBN 128
#define GBK 16

typedef _Float16 h2_t __attribute__((ext_vector_type(2)));

__global__ __launch_bounds__(256) void gates_gemm(
    const float* __restrict__ A,    // [T][IN]
    const float* __restrict__ W,    // [FH][IN]
    const float* __restrict__ bih,  // [FH]
    const float* __restrict__ bhh,  // [FH]
    float* __restrict__ XG,         // [T][FH]  (permuted columns)
    int T, int IN, int FH)
{
    __shared__ __align__(16) float As[GBK][GBM];
    __shared__ __align__(16) float Bs[GBK][GBN];
    const int bm = blockIdx.x * GBM;
    const int bn = blockIdx.y * GBN;
    const int tid = (int)threadIdx.x;
    const int tx = tid & 15, ty = tid >> 4;
    const int H = FH >> 2;   // 100

    float acc[8][8];
    #pragma unroll
    for (int i = 0; i < 8; ++i)
        #pragma unroll
        for (int j = 0; j < 8; ++j) acc[i][j] = 0.f;

    for (int k0 = 0; k0 < IN; k0 += GBK) {
        __syncthreads();
        #pragma unroll
        for (int q = 0; q < 2; ++q) {
            int idx = tid + q * 256;
            int row = idx >> 2;
            int kq  = (idx & 3) << 2;
            int gk  = k0 + kq;
            float4 av = make_float4(0.f, 0.f, 0.f, 0.f);
            float4 bv = make_float4(0.f, 0.f, 0.f, 0.f);
            if (gk < IN) {
                av = *(const float4*)&A[(size_t)(bm + row) * IN + gk];
                if (bn + row < FH)
                    bv = *(const float4*)&W[(size_t)(bn + row) * IN + gk];
            }
            As[kq + 0][row] = av.x; As[kq + 1][row] = av.y;
            As[kq + 2][row] = av.z; As[kq + 3][row] = av.w;
            Bs[kq + 0][row] = bv.x; Bs[kq + 1][row] = bv.y;
            Bs[kq + 2][row] = bv.z; Bs[kq + 3][row] = bv.w;
        }
        __syncthreads();
        #pragma unroll
        for (int kk = 0; kk < GBK; ++kk) {
            float4 a0 = *(const float4*)&As[kk][ty * 4];
            float4 a1 = *(const float4*)&As[kk][64 + ty * 4];
            float4 b0 = *(const float4*)&Bs[kk][tx * 4];
            float4 b1 = *(const float4*)&Bs[kk][64 + tx * 4];
            float am[8] = {a0.x, a0.y, a0.z, a0.w, a1.x, a1.y, a1.z, a1.w};
            float bn_[8] = {b0.x, b0.y, b0.z, b0.w, b1.x, b1.y, b1.z, b1.w};
            #pragma unroll
            for (int i = 0; i < 8; ++i)
                #pragma unroll
                for (int j = 0; j < 8; ++j)
                    acc[i][j] = fmaf(am[i], bn_[j], acc[i][j]);
        }
    }

    #pragma unroll
    for (int i = 0; i < 8; ++i) {
        int r = bm + ((i < 4) ? (ty * 4 + i) : (64 + ty * 4 + (i - 4)));
        #pragma unroll
        for (int j = 0; j < 8; ++j) {
            int cidx = bn + ((j < 4) ? (tx * 4 + j) : (64 + tx * 4 + (j - 4)));
            if (cidx < FH) {
                int pc = 4 * (cidx % H) + cidx / H;   // unit-major permutation
                XG[(size_t)r * FH + pc] = acc[i][j] + bih[cidx] + bhh[cidx];
            }
        }
    }
}

__device__ __forceinline__ float sigmoid_fast(float x) {
    return 1.f / (1.f + __expf(-x));
}
__device__ __forceinline__ float tanh_fast(float x) {
    return 1.f - 2.f / (__expf(2.f * x) + 1.f);
}

// pack W[k], W[k+1] (f32) into one dword of two f16 (k, k+1 < 100 here)
__device__ __forceinline__ float pack_pair(const float* rp, int k) {
    h2_t p = {(_Float16)rp[k], (_Float16)rp[k + 1]};
    return __builtin_bit_cast(float, p);
}

// write one weight dword into a PHYSICAL VGPR (once, at startup)
#define INITW(R, V) \
    asm volatile("v_mov_b32 v" #R ", %0" :: "v"(V) : "v" #R)

// one dot2 line: vA += vW . vH  (all physical registers)
#define DD(A, W, Hr) "v_dot2_f32_f16 v" #A ", v" #W ", v" #Hr ", v" #A "\n\t"

// one h-dword: 4 dot2 (one per gate row), round-robin accumulators
#define Q4(H, WI, WF, WG, WO) \
    DD(148,WI,H) DD(149,WF,H) DD(150,WG,H) DD(151,WO,H)

// clobbers: v96..v120 (h), v148..v151 (acc), v152..v251 (weights)
#define VCLOB \
  "v96","v97","v98","v99","v100","v101","v102","v103","v104","v105","v106",\
  "v107","v108","v109","v110","v111","v112","v113","v114","v115","v116",\
  "v117","v118","v119","v120",\
  "v148","v149","v150","v151","v152","v153","v154","v155","v156",\
  "v157","v158","v159","v160","v161","v162","v163","v164","v165","v166",\
  "v167","v168","v169","v170","v171","v172","v173","v174","v175","v176",\
  "v177","v178","v179","v180","v181","v182","v183","v184","v185","v186",\
  "v187","v188","v189","v190","v191","v192","v193","v194","v195","v196",\
  "v197","v198","v199","v200","v201","v202","v203","v204","v205","v206",\
  "v207","v208","v209","v210","v211","v212","v213","v214","v215","v216",\
  "v217","v218","v219","v220","v221","v222","v223","v224","v225","v226",\
  "v227","v228","v229","v230","v231","v232","v233","v234","v235","v236",\
  "v237","v238","v239","v240","v241","v242","v243","v244","v245","v246",\
  "v247","v248","v249","v250","v251"

// raw barrier: orders LDS, leaves global loads in flight
#define BAR() asm volatile("s_waitcnt lgkmcnt(0)\n\ts_barrier" ::: "memory")

__global__ __launch_bounds__(256, 1) void lstm_scan_ksplit(
    const float* __restrict__ XGp,   // [T][400] permuted (4u+g)
    const float* __restrict__ Whh,   // [400][100] original layout
    const float* __restrict__ wlin,  // [100]
    const float* __restrict__ blin,  // [1]
    float* __restrict__ out, int T)
{
    // h: 2 buffers x 2 K-half slices x 112 B (56 halves; 50 used + pad)
    __shared__ __align__(16) _Float16 hbuf[2][112];
    __shared__ float hfin[100];
    const int tid = (int)threadIdx.x;
    const int ph  = tid & 1;             // K-half: 0 -> k<50, 1 -> k>=50
    const int u   = tid >> 1;            // unit index
    const int uc  = (u < 100) ? u : 99;  // clamp
    const bool act = (ph == 0) && (u < 100);
    const int ko  = 50 * ph;             // k offset of this thread's half

    // all 4 gate rows of unit uc (original layout)
    const float* ri = Whh + (size_t)(uc)       * 100;
    const float* rf = Whh + (size_t)(uc + 100) * 100;
    const float* rg = Whh + (size_t)(uc + 200) * 100;
    const float* ro = Whh + (size_t)(uc + 300) * 100;

    // ---- weights into PHYSICAL VGPRs: i->v152+j f->v177+j g->v202+j o->v227+j
#define LWX(j, RI, RF, RG, RO) { \
    INITW(RI, pack_pair(ri, ko + 2*(j))); \
    INITW(RF, pack_pair(rf, ko + 2*(j))); \
    INITW(RG, pack_pair(rg, ko + 2*(j))); \
    INITW(RO, pack_pair(ro, ko + 2*(j))); }
    LWX(0,152,177,202,227)  LWX(1,153,178,203,228)  LWX(2,154,179,204,229)
    LWX(3,155,180,205,230)  LWX(4,156,181,206,231)  LWX(5,157,182,207,232)
    LWX(6,158,183,208,233)  LWX(7,159,184,209,234)  LWX(8,160,185,210,235)
    LWX(9,161,186,211,236)  LWX(10,162,187,212,237) LWX(11,163,188,213,238)
    LWX(12,164,189,214,239) LWX(13,165,190,215,240) LWX(14,166,191,216,241)
    LWX(15,167,192,217,242) LWX(16,168,193,218,243) LWX(17,169,194,219,244)
    LWX(18,170,195,220,245) LWX(19,171,196,221,246) LWX(20,172,197,222,247)
    LWX(21,173,198,223,248) LWX(22,174,199,224,249) LWX(23,175,200,225,250)
    LWX(24,176,201,226,251)
#undef LWX

    if (tid < 112) { hbuf[0][tid] = (_Float16)0.f; hbuf[1][tid] = (_Float16)0.f; }

    const unsigned hb_base = (unsigned)(uintptr_t)&hbuf[0][0];
    const unsigned hb_par  = hb_base + (unsigned)(112 * ph);

    // xg: permuted float4 (xi,xf,xg,xo) of unit uc; both pair lanes load the
    // same address (broadcast); odd lane passes zeros into the accumulators
    // so the pair-sum counts xg exactly once.
#define XR(i) (*(const float4*)(XGp + (size_t)((i) < T ? (i) : (T - 1)) * 400 + 4 * uc))

    float4 xa = XR(0), xb = XR(1), xc = XR(2), xd = XR(3);

    float c = 0.f, hlast = 0.f;
    int cur = 0;
    BAR();

    // ---- matvec: 7 h reads + 100 dot2 + in-asm DPP pair-combine ----
#define MATVEC4(G0, G1, G2, G3, HB, X0, X1, X2, X3) \
    asm volatile( \
        "v_mov_b32 v148, %[x0]\n\t" \
        "v_mov_b32 v149, %[x1]\n\t" \
        "v_mov_b32 v150, %[x2]\n\t" \
        "v_mov_b32 v151, %[x3]\n\t" \
        "ds_read_b128 v[96:99], %[hb]\n\t" \
        "ds_read_b128 v[100:103], %[hb] offset:16\n\t" \
        "ds_read_b128 v[104:107], %[hb] offset:32\n\t" \
        "ds_read_b128 v[108:111], %[hb] offset:48\n\t" \
        "ds_read_b128 v[112:115], %[hb] offset:64\n\t" \
        "ds_read_b128 v[116:119], %[hb] offset:80\n\t" \
        "ds_read_b32 v120, %[hb] offset:96\n\t" \
        "s_waitcnt lgkmcnt(3)\n\t" \
        Q4(96,152,177,202,227)   Q4(97,153,178,203,228) \
        Q4(98,154,179,204,229)   Q4(99,155,180,205,230) \
        Q4(100,156,181,206,231)  Q4(101,157,182,207,232) \
        Q4(102,158,183,208,233)  Q4(103,159,184,209,234) \
        Q4(104,160,185,210,235)  Q4(105,161,186,211,236) \
        Q4(106,162,187,212,237)  Q4(107,163,188,213,238) \
        Q4(108,164,189,214,239)  Q4(109,165,190,215,240) \
        Q4(110,166,191,216,241)  Q4(111,167,192,217,242) \
        "s_waitcnt lgkmcnt(0)\n\t" \
        Q4(112,168,193,218,243)  Q4(113,169,194,219,244) \
        Q4(114,170,195,220,245)  Q4(115,171,196,221,246) \
        Q4(116,172,197,222,247)  Q4(117,173,198,223,248) \
        Q4(118,174,199,224,249)  Q4(119,175,200,225,250) \
        Q4(120,176,201,226,251) \
        "s_nop 1\n\t" \
        "v_add_f32 %[g0], v148, v148 quad_perm:[1,0,3,2] row_mask:0xf bank_mask:0xf\n\t" \
        "v_add_f32 %[g1], v149, v149 quad_perm:[1,0,3,2] row_mask:0xf bank_mask:0xf\n\t" \
        "v_add_f32 %[g2], v150, v150 quad_perm:[1,0,3,2] row_mask:0xf bank_mask:0xf\n\t" \
        "v_add_f32 %[g3], v151, v151 quad_perm:[1,0,3,2] row_mask:0xf bank_mask:0xf" \
        : [g0]"=v"(G0), [g1]"=v"(G1), [g2]"=v"(G2), [g3]"=v"(G3) \
        : [hb]"v"(HB), [x0]"v"(X0), [x1]"v"(X1), [x2]"v"(X2), [x3]"v"(X3) \
        : VCLOB, "memory")

#define SUBSTEP(XP, TNEXT) { \
    unsigned hb_ = hb_par + (unsigned)(cur * 224); \
    float x0_ = ph ? 0.f : XP.x; \
    float x1_ = ph ? 0.f : XP.y; \
    float x2_ = ph ? 0.f : XP.z; \
    float x3_ = ph ? 0.f : XP.w; \
    float g0, g1, g2, g3; \
    MATVEC4(g0, g1, g2, g3, hb_, x0_, x1_, x2_, x3_); \
    XP = XR(TNEXT);   /* direct load into named reg; next use 4 steps away */ \
    float iv = sigmoid_fast(g0); \
    float fv = sigmoid_fast(g1); \
    float gv = tanh_fast(g2); \
    float ov = sigmoid_fast(g3); \
    c = fmaf(fv, c, iv * gv); \
    float hv_ = ov * tanh_fast(c); \
    if (act) { \
        hlast = hv_; \
        int hidx = (u < 50) ? u : (u + 6);   /* slice layout: 56-half slices */ \
        hbuf[cur ^ 1][hidx] = (_Float16)hv_; \
    } \
    BAR(); \
    cur ^= 1; }

    for (int t = 0; t < T; t += 4) {
        SUBSTEP(xa, t + 4)
        SUBSTEP(xb, t + 5)
        SUBSTEP(xc, t + 6)
        SUBSTEP(xd, t + 7)
    }
#undef SUBSTEP
#undef XR

    if (act) hfin[u] = hlast * wlin[u];
    __syncthreads();
    if (tid == 0) {
        float s = blin[0];
        for (int k = 0; k < 100; ++k) s += hfin[k];
        out[0] = s;
    }
}

extern "C" void kernel_launch(void* const* d_in, const int* in_sizes, int n_in,
                              void* d_out, int out_size, void* d_ws, size_t ws_size,
                              hipStream_t stream) {
    const float* input = (const float*)d_in[0];  // [T][IN]
    const float* w_ih  = (const float*)d_in[1];  // [4H][IN]
    const float* w_hh  = (const float*)d_in[2];  // [4H][H]
    const float* b_ih  = (const float*)d_in[3];  // [4H]
    const float* b_hh  = (const float*)d_in[4];  // [4H]
    const float* w_lin = (const float*)d_in[5];  // [H]
    const float* b_lin = (const float*)d_in[6];  // [1]
    float* out = (float*)d_out;

    const int FH = in_sizes[3];            // 400
    const int IN = in_sizes[1] / FH;       // 3000
    const int T  = in_sizes[0] / IN;       // 8192

    float* xg = (float*)d_ws;              // [T][FH] = 13.1 MB (permuted)

    dim3 grid((T + GBM - 1) / GBM, (FH + GBN - 1) / GBN);
    gates_gemm<<<grid, 256, 0, stream>>>(input, w_ih, b_ih, b_hh, xg, T, IN, FH);
    lstm_scan_ksplit<<<1, 256, 0, stream>>>(xg, w_hh, w_lin, b_lin, out, T);
}

// Round 22
// 4021.272 us; speedup vs baseline: 1.1573x; 1.1573x over previous
//
#include <hip/hip_runtime.h>
#include <hip/hip_bf16.h>

// LSTM: T=8192, IN=3000, H=100 (4H=400), torch gate order i,f,g,o.
// Phase 1: xg[T][400] = input @ w_ih^T + (b_ih+b_hh), PERMUTED cols (4u+g).
// Phase 2: single-workgroup scan, 256 threads / 4 waves, VALU dot2 engine,
//          weights pinned in PHYSICAL VGPRs v152..v255 (R16/R20-proven).
// ROUND-22: banked R20 + ONE change: the ds_swizzle gate exchange (~120cyc
// LDS latency on the serial tail) is replaced by two in-asm DPP
// v_mov_b32 quad_perm:[1,0,3,2] movs with an s_nop guard. R21 PASSED
// (absmax 0) using exactly this in-asm nop-guarded DPP mechanism, so it is
// HW-verified in this kernel family (R17's failure used the compiler-placed
// builtin instead). Lanes 2p/2p+1 share a quad and all lanes are active at
// the exchange point, so quad_perm [1,0,3,2] == the xor-1 exchange.
// R21's K-split structure itself REGRESSED (doubled transcendental work,
// no pipe win) and is reverted.
//   v96..v147  = 13x ds_read_b128 of h (f16, LDS double buffer)
//   v148..v151 = 4 interleaved dot2 accumulator chains
//   counted lgkmcnt(9/5/1/0) waits (R16-proven granularity)
// Scaffolding: lane-pair unit layout (even lane: gates i,f; odd: g,o),
// divergence-free unified nonlinearity, lgkmcnt-only barrier, depth-4
// direct-load xg prefetch.

#define GBM 128
#define GBN 128
#define GBK 16

typedef _Float16 h2_t __attribute__((ext_vector_type(2)));

__global__ __launch_bounds__(256) void gates_gemm(
    const float* __restrict__ A,    // [T][IN]
    const float* __restrict__ W,    // [FH][IN]
    const float* __restrict__ bih,  // [FH]
    const float* __restrict__ bhh,  // [FH]
    float* __restrict__ XG,         // [T][FH]  (permuted columns)
    int T, int IN, int FH)
{
    __shared__ __align__(16) float As[GBK][GBM];
    __shared__ __align__(16) float Bs[GBK][GBN];
    const int bm = blockIdx.x * GBM;
    const int bn = blockIdx.y * GBN;
    const int tid = (int)threadIdx.x;
    const int tx = tid & 15, ty = tid >> 4;
    const int H = FH >> 2;   // 100

    float acc[8][8];
    #pragma unroll
    for (int i = 0; i < 8; ++i)
        #pragma unroll
        for (int j = 0; j < 8; ++j) acc[i][j] = 0.f;

    for (int k0 = 0; k0 < IN; k0 += GBK) {
        __syncthreads();
        #pragma unroll
        for (int q = 0; q < 2; ++q) {
            int idx = tid + q * 256;
            int row = idx >> 2;
            int kq  = (idx & 3) << 2;
            int gk  = k0 + kq;
            float4 av = make_float4(0.f, 0.f, 0.f, 0.f);
            float4 bv = make_float4(0.f, 0.f, 0.f, 0.f);
            if (gk < IN) {
                av = *(const float4*)&A[(size_t)(bm + row) * IN + gk];
                if (bn + row < FH)
                    bv = *(const float4*)&W[(size_t)(bn + row) * IN + gk];
            }
            As[kq + 0][row] = av.x; As[kq + 1][row] = av.y;
            As[kq + 2][row] = av.z; As[kq + 3][row] = av.w;
            Bs[kq + 0][row] = bv.x; Bs[kq + 1][row] = bv.y;
            Bs[kq + 2][row] = bv.z; Bs[kq + 3][row] = bv.w;
        }
        __syncthreads();
        #pragma unroll
        for (int kk = 0; kk < GBK; ++kk) {
            float4 a0 = *(const float4*)&As[kk][ty * 4];
            float4 a1 = *(const float4*)&As[kk][64 + ty * 4];
            float4 b0 = *(const float4*)&Bs[kk][tx * 4];
            float4 b1 = *(const float4*)&Bs[kk][64 + tx * 4];
            float am[8] = {a0.x, a0.y, a0.z, a0.w, a1.x, a1.y, a1.z, a1.w};
            float bn_[8] = {b0.x, b0.y, b0.z, b0.w, b1.x, b1.y, b1.z, b1.w};
            #pragma unroll
            for (int i = 0; i < 8; ++i)
                #pragma unroll
                for (int j = 0; j < 8; ++j)
                    acc[i][j] = fmaf(am[i], bn_[j], acc[i][j]);
        }
    }

    #pragma unroll
    for (int i = 0; i < 8; ++i) {
        int r = bm + ((i < 4) ? (ty * 4 + i) : (64 + ty * 4 + (i - 4)));
        #pragma unroll
        for (int j = 0; j < 8; ++j) {
            int cidx = bn + ((j < 4) ? (tx * 4 + j) : (64 + tx * 4 + (j - 4)));
            if (cidx < FH) {
                int pc = 4 * (cidx % H) + cidx / H;   // unit-major permutation
                XG[(size_t)r * FH + pc] = acc[i][j] + bih[cidx] + bhh[cidx];
            }
        }
    }
}

// pack W[k], W[k+1] (f32) into one dword of two f16 (zero past K=100)
__device__ __forceinline__ float pack_pair(const float* rp, int k) {
    float a = 0.f, b = 0.f;
    if (k < 100) { a = rp[k]; b = rp[k + 1]; }
    h2_t p = {(_Float16)a, (_Float16)b};
    return __builtin_bit_cast(float, p);
}

// write one weight dword into a PHYSICAL VGPR (once, at startup)
#define INITW(R, V) \
    asm volatile("v_mov_b32 v" #R ", %0" :: "v"(V) : "v" #R)

// one dot2 line: vA += vW . vH  (all physical registers)
#define DD(A, W, Hr) "v_dot2_f32_f16 v" #A ", v" #W ", v" #Hr ", v" #A "\n\t"

// clobbers: everything the big block owns (v96..v255)
#define VCLOB \
  "v96","v97","v98","v99","v100","v101","v102","v103","v104","v105","v106",\
  "v107","v108","v109","v110","v111","v112","v113","v114","v115","v116",\
  "v117","v118","v119","v120","v121","v122","v123","v124","v125","v126",\
  "v127","v128","v129","v130","v131","v132","v133","v134","v135","v136",\
  "v137","v138","v139","v140","v141","v142","v143","v144","v145","v146",\
  "v147","v148","v149","v150","v151","v152","v153","v154","v155","v156",\
  "v157","v158","v159","v160","v161","v162","v163","v164","v165","v166",\
  "v167","v168","v169","v170","v171","v172","v173","v174","v175","v176",\
  "v177","v178","v179","v180","v181","v182","v183","v184","v185","v186",\
  "v187","v188","v189","v190","v191","v192","v193","v194","v195","v196",\
  "v197","v198","v199","v200","v201","v202","v203","v204","v205","v206",\
  "v207","v208","v209","v210","v211","v212","v213","v214","v215","v216",\
  "v217","v218","v219","v220","v221","v222","v223","v224","v225","v226",\
  "v227","v228","v229","v230","v231","v232","v233","v234","v235","v236",\
  "v237","v238","v239","v240","v241","v242","v243","v244","v245","v246",\
  "v247","v248","v249","v250","v251","v252","v253","v254","v255"

// raw barrier: orders LDS, leaves global loads in flight
#define BAR() asm volatile("s_waitcnt lgkmcnt(0)\n\ts_barrier" ::: "memory")

__global__ __launch_bounds__(256, 1) void lstm_scan_pinv5(
    const float* __restrict__ XGp,   // [T][400] permuted (4u+g)
    const float* __restrict__ Whh,   // [400][100] original layout
    const float* __restrict__ wlin,  // [100]
    const float* __restrict__ blin,  // [1]
    float* __restrict__ out, int T)
{
    __shared__ __align__(16) _Float16 hbuf[2][104];  // 208 B per buffer
    __shared__ float hfin[100];
    const int tid    = (int)threadIdx.x;
    const int parity = tid & 1;          // 0: gates i,f   1: gates g,o
    const int p      = tid >> 1;         // unit index
    const int pc     = (p < 100) ? p : 99;
    const bool act   = (parity == 0) && (p < 100);
    const float kk   = 1.f + (float)parity;   // 1 -> sigmoid, 2 -> tanh

    // gate rows: even = (u, u+100) = (i,f); odd = (u+200, u+300) = (g,o)
    const float* r0p = Whh + (size_t)(pc + parity * 200) * 100;
    const float* r1p = Whh + (size_t)(pc + 100 + parity * 200) * 100;

    // ---- weights into PHYSICAL VGPRs: row0 -> v152+j, row1 -> v204+j ----
#define LW(j, R0, R1) { INITW(R0, pack_pair(r0p, 2*(j))); \
                        INITW(R1, pack_pair(r1p, 2*(j))); }
    LW(0,152,204)  LW(1,153,205)  LW(2,154,206)  LW(3,155,207)
    LW(4,156,208)  LW(5,157,209)  LW(6,158,210)  LW(7,159,211)
    LW(8,160,212)  LW(9,161,213)  LW(10,162,214) LW(11,163,215)
    LW(12,164,216) LW(13,165,217) LW(14,166,218) LW(15,167,219)
    LW(16,168,220) LW(17,169,221) LW(18,170,222) LW(19,171,223)
    LW(20,172,224) LW(21,173,225) LW(22,174,226) LW(23,175,227)
    LW(24,176,228) LW(25,177,229) LW(26,178,230) LW(27,179,231)
    LW(28,180,232) LW(29,181,233) LW(30,182,234) LW(31,183,235)
    LW(32,184,236) LW(33,185,237) LW(34,186,238) LW(35,187,239)
    LW(36,188,240) LW(37,189,241) LW(38,190,242) LW(39,191,243)
    LW(40,192,244) LW(41,193,245) LW(42,194,246) LW(43,195,247)
    LW(48,200,252) LW(44,196,248) LW(45,197,249) LW(46,198,250)
    LW(47,199,251) LW(49,201,253) LW(50,202,254) LW(51,203,255)
#undef LW

    if (tid < 104) { hbuf[0][tid] = (_Float16)0.f; hbuf[1][tid] = (_Float16)0.f; }

    const unsigned hb_base = (unsigned)(uintptr_t)&hbuf[0][0];

    // xg: even lane reads permuted cols (4u,4u+1)=(i,f); odd (4u+2,4u+3)=(g,o)
    const int xoff = 4 * pc + 2 * parity;
#define XR(i) (*(const float2*)(XGp + (size_t)((i) < T ? (i) : (T - 1)) * 400 + xoff))

    float2 xa = XR(0), xb = XR(1), xc = XR(2), xd = XR(3);

    float c = 0.f, hlast = 0.f;
    int cur = 0;
    BAR();

    // ---- the whole matvec: one asm block (h loads + 104 dot2) ----
#define MATVEC(G0, G1, HB, X0, X1) \
    asm volatile( \
        "v_mov_b32 v148, %[x0]\n\t" \
        "v_mov_b32 v149, %[x1]\n\t" \
        "v_mov_b32 v150, 0\n\t" \
        "v_mov_b32 v151, 0\n\t" \
        "ds_read_b128 v[96:99], %[hb]\n\t" \
        "ds_read_b128 v[100:103], %[hb] offset:16\n\t" \
        "ds_read_b128 v[104:107], %[hb] offset:32\n\t" \
        "ds_read_b128 v[108:111], %[hb] offset:48\n\t" \
        "ds_read_b128 v[112:115], %[hb] offset:64\n\t" \
        "ds_read_b128 v[116:119], %[hb] offset:80\n\t" \
        "ds_read_b128 v[120:123], %[hb] offset:96\n\t" \
        "ds_read_b128 v[124:127], %[hb] offset:112\n\t" \
        "ds_read_b128 v[128:131], %[hb] offset:128\n\t" \
        "ds_read_b128 v[132:135], %[hb] offset:144\n\t" \
        "ds_read_b128 v[136:139], %[hb] offset:160\n\t" \
        "ds_read_b128 v[140:143], %[hb] offset:176\n\t" \
        "ds_read_b128 v[144:147], %[hb] offset:192\n\t" \
        "s_waitcnt lgkmcnt(9)\n\t" \
        DD(148,152,96)  DD(149,204,96)  DD(150,153,97)  DD(151,205,97) \
        DD(148,154,98)  DD(149,206,98)  DD(150,155,99)  DD(151,207,99) \
        DD(148,156,100) DD(149,208,100) DD(150,157,101) DD(151,209,101) \
        DD(148,158,102) DD(149,210,102) DD(150,159,103) DD(151,211,103) \
        DD(148,160,104) DD(149,212,104) DD(150,161,105) DD(151,213,105) \
        DD(148,162,106) DD(149,214,106) DD(150,163,107) DD(151,215,107) \
        DD(148,164,108) DD(149,216,108) DD(150,165,109) DD(151,217,109) \
        DD(148,166,110) DD(149,218,110) DD(150,167,111) DD(151,219,111) \
        "s_waitcnt lgkmcnt(5)\n\t" \
        DD(148,168,112) DD(149,220,112) DD(150,169,113) DD(151,221,113) \
        DD(148,170,114) DD(149,222,114) DD(150,171,115) DD(151,223,115) \
        DD(148,172,116) DD(149,224,116) DD(150,173,117) DD(151,225,117) \
        DD(148,174,118) DD(149,226,118) DD(150,175,119) DD(151,227,119) \
        DD(148,176,120) DD(149,228,120) DD(150,177,121) DD(151,229,121) \
        DD(148,178,122) DD(149,230,122) DD(150,179,123) DD(151,231,123) \
        DD(148,180,124) DD(149,232,124) DD(150,181,125) DD(151,233,125) \
        DD(148,182,126) DD(149,234,126) DD(150,183,127) DD(151,235,127) \
        "s_waitcnt lgkmcnt(1)\n\t" \
        DD(148,184,128) DD(149,236,128) DD(150,185,129) DD(151,237,129) \
        DD(148,186,130) DD(149,238,130) DD(150,187,131) DD(151,239,131) \
        DD(148,188,132) DD(149,240,132) DD(150,189,133) DD(151,241,133) \
        DD(148,190,134) DD(149,242,134) DD(150,191,135) DD(151,243,135) \
        DD(148,192,136) DD(149,244,136) DD(150,193,137) DD(151,245,137) \
        DD(148,194,138) DD(149,246,138) DD(150,195,139) DD(151,247,139) \
        DD(148,196,140) DD(149,248,140) DD(150,197,141) DD(151,249,141) \
        DD(148,198,142) DD(149,250,142) DD(150,199,143) DD(151,251,143) \
        "s_waitcnt lgkmcnt(0)\n\t" \
        DD(148,200,144) DD(149,252,144) DD(150,201,145) DD(151,253,145) \
        DD(148,202,146) DD(149,254,146) DD(150,203,147) DD(151,255,147) \
        "v_add_f32 %[g0], v148, v150\n\t" \
        "v_add_f32 %[g1], v149, v151" \
        : [g0]"=v"(G0), [g1]"=v"(G1) \
        : [hb]"v"(HB), [x0]"v"(X0), [x1]"v"(X1) \
        : VCLOB, "memory")

#define SUBSTEP(XP, TNEXT) { \
    unsigned hb_ = hb_base + (unsigned)(cur * 208); \
    float g0, g1; \
    MATVEC(g0, g1, hb_, XP.x, XP.y); \
    XP = XR(TNEXT);   /* direct load into named reg; next use 4 steps away */ \
    /* unified nonlinearity: even->sigmoid(g0)=iv, odd->tanh(g0)=gv */ \
    float e0  = __expf(kk * g0); \
    float t0v = 1.f - kk * __builtin_amdgcn_rcpf(e0 + 1.f); \
    float e1  = __expf(-g1); \
    float t1v = __builtin_amdgcn_rcpf(1.f + e1);   /* s(f) / s(o) */ \
    /* exchange with partner lane (xor 1) via in-asm nop-guarded DPP */ \
    /* (mechanism HW-verified by R21's pass; all lanes active here) */ \
    float rg_, ro_; \
    asm volatile("s_nop 3\n\t" \
                 "v_mov_b32 %0, %2 quad_perm:[1,0,3,2] row_mask:0xf bank_mask:0xf\n\t" \
                 "v_mov_b32 %1, %3 quad_perm:[1,0,3,2] row_mask:0xf bank_mask:0xf" \
                 : "=v"(rg_), "=v"(ro_) : "v"(t0v), "v"(t1v)); \
    c = fmaf(t1v, c, t0v * rg_);          /* fv*c + iv*gv (even lanes) */ \
    float e2 = __expf(2.f * c); \
    float th = 1.f - 2.f * __builtin_amdgcn_rcpf(e2 + 1.f); \
    float hv_ = ro_ * th;                 /* ov * tanh(c) */ \
    if (act) { hlast = hv_; hbuf[cur ^ 1][p] = (_Float16)hv_; } \
    BAR(); \
    cur ^= 1; }

    for (int t = 0; t < T; t += 4) {
        SUBSTEP(xa, t + 4)
        SUBSTEP(xb, t + 5)
        SUBSTEP(xc, t + 6)
        SUBSTEP(xd, t + 7)
    }
#undef SUBSTEP
#undef XR

    if (act) hfin[p] = hlast * wlin[p];
    __syncthreads();
    if (tid == 0) {
        float s = blin[0];
        for (int k = 0; k < 100; ++k) s += hfin[k];
        out[0] = s;
    }
}

extern "C" void kernel_launch(void* const* d_in, const int* in_sizes, int n_in,
                              void* d_out, int out_size, void* d_ws, size_t ws_size,
                              hipStream_t stream) {
    const float* input = (const float*)d_in[0];  // [T][IN]
    const float* w_ih  = (const float*)d_in[1];  // [4H][IN]
    const float* w_hh  = (const float*)d_in[2];  // [4H][H]
    const float* b_ih  = (const float*)d_in[3];  // [4H]
    const float* b_hh  = (const float*)d_in[4];  // [4H]
    const float* w_lin = (const float*)d_in[5];  // [H]
    const float* b_lin = (const float*)d_in[6];  // [1]
    float* out = (float*)d_out;

    const int FH = in_sizes[3];            // 400
    const int IN = in_sizes[1] / FH;       // 3000
    const int T  = in_sizes[0] / IN;       // 8192

    float* xg = (float*)d_ws;              // [T][FH] = 13.1 MB (permuted)

    dim3 grid((T + GBM - 1) / GBM, (FH + GBN - 1) / GBN);
    gates_gemm<<<grid, 256, 0, stream>>>(input, w_ih, b_ih, b_hh, xg, T, IN, FH);
    lstm_scan_pinv5<<<1, 256, 0, stream>>>(xg, w_hh, w_lin, b_lin, out, T);
}